// Round 1
// baseline (1147.990 us; speedup 1.0000x reference)
//
#include <hip/hip_runtime.h>
#include <hip/hip_bf16.h>
#include <math.h>

// Problem constants
#define B 16
#define S 4096
#define D 64
#define NH 8
#define NBUCK 64          // buckets per hash
#define CHUNKS 512        // chunks per batch (NH * NBUCK)
#define BS 64             // bucket/chunk size

// ---------------------------------------------------------------------------
// Kernel 1: hashing. rotated = qk . rot (f64 accumulate for argmax stability),
// bucket = argmax([r, -r]) with first-occurrence tie rules.
// grid: B*NH*4 blocks (each block: 1024 tokens), 256 threads.
// ---------------------------------------------------------------------------
__global__ __launch_bounds__(256) void hash_kernel(
    const float* __restrict__ qk, const float* __restrict__ rot,
    float* __restrict__ out_buckets, int* __restrict__ bucket_ws)
{
    __shared__ double R[64 * 32];   // R[f*32+i], 16 KB
    int tid = threadIdx.x;
    int bid = blockIdx.x;
    int b   = bid >> 5;
    int h   = (bid >> 2) & 7;
    int qtr = bid & 3;

    // stage rotations for this hash round, widened to f64
    for (int e = tid; e < 2048; e += 256) {
        int f = e >> 5, i = e & 31;
        R[e] = (double)rot[f * (NH * 32) + h * 32 + i];
    }
    __syncthreads();

    for (int k = 0; k < 4; ++k) {
        int t = qtr * 1024 + k * 256 + tid;
        const float4* rowp = (const float4*)(qk + ((size_t)b * S + t) * D);
        double acc[32];
        #pragma unroll
        for (int i = 0; i < 32; ++i) acc[i] = 0.0;

        for (int k2 = 0; k2 < 16; ++k2) {
            float4 x4 = rowp[k2];
            float xs[4] = {x4.x, x4.y, x4.z, x4.w};
            #pragma unroll
            for (int u = 0; u < 4; ++u) {
                double x = (double)xs[u];
                const double* Rr = &R[(k2 * 4 + u) * 32];
                #pragma unroll
                for (int i = 0; i < 32; ++i)
                    acc[i] = __fma_rn(x, Rr[i], acc[i]);
            }
        }
        // argmax over [acc, -acc], first occurrence wins on ties
        double best = acc[0]; int bi = 0;
        double worst = acc[0]; int wi = 0;
        #pragma unroll
        for (int i = 1; i < 32; ++i) {
            if (acc[i] > best)  { best = acc[i]; bi = i; }
            if (acc[i] < worst) { worst = acc[i]; wi = i; }
        }
        int bucket = (-worst > best) ? (32 + wi) : bi;
        size_t idx = (size_t)(b * NH + h) * S + t;
        bucket_ws[idx] = bucket;
        out_buckets[idx] = (float)(bucket + h * NBUCK);
    }
}

// ---------------------------------------------------------------------------
// Kernel 2: stable counting sort per (b,h): st_ws[pos] = original t,
// sorted by (bucket, t). grid: B*NH blocks, 64 threads (one wave).
// Lane i owns bucket i.
// ---------------------------------------------------------------------------
__global__ __launch_bounds__(64) void sort_kernel(
    const int* __restrict__ bucket_ws, int* __restrict__ st_ws)
{
    __shared__ int sb[S];
    __shared__ int cnt[64];
    int tid = threadIdx.x;
    int base = blockIdx.x * S;    // blockIdx.x == b*NH + h

    cnt[tid] = 0;
    __syncthreads();
    for (int t = tid; t < S; t += 64) {
        int vb = bucket_ws[base + t];
        sb[t] = vb;
        atomicAdd(&cnt[vb], 1);
    }
    __syncthreads();
    // exclusive prefix for this lane's bucket
    int myb = 0;
    for (int j = 0; j < 64; ++j) {
        int cj = cnt[j];
        if (j < tid) myb += cj;
    }
    int idx = myb;
    const int4* sb4 = (const int4*)sb;
    for (int t4 = 0; t4 < S / 4; ++t4) {
        int4 q = sb4[t4];       // broadcast LDS read (all lanes same addr)
        int t = t4 * 4;
        if (q.x == tid) st_ws[base + idx++] = t;
        if (q.y == tid) st_ws[base + idx++] = t + 1;
        if (q.z == tid) st_ws[base + idx++] = t + 2;
        if (q.w == tid) st_ws[base + idx++] = t + 3;
    }
}

// ---------------------------------------------------------------------------
// Kernel 3: per-chunk attention. grid: B*CHUNKS blocks, 256 threads.
// Keys = [current chunk (64), previous chunk (64)] (wraparound over c).
// q_i . k_j computed as ||q_i|| * (k_i . k_j). Self-mask: t_q == t_k -> -1e5.
// ---------------------------------------------------------------------------
#define KSTR 68     // padded LDS row stride (floats) to break bank conflicts

__global__ __launch_bounds__(256, 1) void attn_kernel(
    const float* __restrict__ qk, const float* __restrict__ v,
    const int* __restrict__ st_ws,
    float* __restrict__ o_ws, float* __restrict__ logits_ws)
{
    __shared__ float Ks[128 * KSTR];   // normalized keys (first 64 rows = queries dir)
    __shared__ float Vs[128 * KSTR];
    __shared__ float Ds[64 * 129];     // dots -> probs
    __shared__ int   tkx[128];         // original positions of the 128 keys
    __shared__ float nq[64];           // query norms
    __shared__ float pmax[4][64], psum[4][64];
    __shared__ float rowm[64], lses[64];

    int tid = threadIdx.x;
    int c = blockIdx.x & (CHUNKS - 1);
    int b = blockIdx.x >> 9;
    int h = c >> 6;
    int sbase = b * (NH * S);

    if (tid < 128) {
        int cc = (tid < 64) ? c : ((c + CHUNKS - 1) & (CHUNKS - 1));
        tkx[tid] = st_ws[sbase + cc * BS + (tid & 63)];
    }
    __syncthreads();

    // stage raw qk rows (as K, to be normalized) and V rows
    {
        int r = tid >> 1, half = tid & 1;
        int tok = tkx[r];
        const float4* qs = (const float4*)(qk + ((size_t)b * S + tok) * D) + half * 8;
        const float4* vsrc = (const float4*)(v + ((size_t)b * S + tok) * D) + half * 8;
        float4* kd = (float4*)(Ks + r * KSTR + half * 32);
        float4* vd = (float4*)(Vs + r * KSTR + half * 32);
        #pragma unroll
        for (int k2 = 0; k2 < 8; ++k2) { kd[k2] = qs[k2]; vd[k2] = vsrc[k2]; }
    }
    __syncthreads();

    // normalize rows of Ks; record query norms
    if (tid < 128) {
        float* row = Ks + tid * KSTR;
        float s = 0.f;
        #pragma unroll
        for (int d = 0; d < 64; d += 4) {
            float4 x = *(float4*)(row + d);
            s += x.x * x.x + x.y * x.y + x.z * x.z + x.w * x.w;
        }
        float nrm = sqrtf(s);
        float inv = 1.0f / fmaxf(nrm, 1e-12f);
        #pragma unroll
        for (int d = 0; d < 64; d += 4) {
            float4 x = *(float4*)(row + d);
            x.x *= inv; x.y *= inv; x.z *= inv; x.w *= inv;
            *(float4*)(row + d) = x;
        }
        if (tid < 64) nq[tid] = nrm;
    }
    __syncthreads();

    int i = tid & 63, part = tid >> 6;

    // load my query direction into registers
    float4 ki[16];
    #pragma unroll
    for (int k2 = 0; k2 < 16; ++k2) ki[k2] = *(const float4*)(Ks + i * KSTR + k2 * 4);
    float scale = nq[i] * 0.125f;     // D^-0.5 = 1/8
    int ti = tkx[i];

    float dv[32];
    for (int jj = 0; jj < 32; ++jj) {
        int j = part * 32 + jj;
        const float4* kr = (const float4*)(Ks + j * KSTR);   // broadcast reads
        float acc = 0.f;
        #pragma unroll
        for (int k2 = 0; k2 < 16; ++k2) {
            float4 kb = kr[k2];
            acc += ki[k2].x * kb.x + ki[k2].y * kb.y + ki[k2].z * kb.z + ki[k2].w * kb.w;
        }
        float dval = acc * scale;
        if (ti == tkx[j]) dval = -1e5f;
        dv[jj] = dval;
    }

    // row max
    float lmax = dv[0];
    #pragma unroll
    for (int jj = 1; jj < 32; ++jj) lmax = fmaxf(lmax, dv[jj]);
    pmax[part][i] = lmax;
    __syncthreads();
    if (part == 0) {
        float m = fmaxf(fmaxf(pmax[0][i], pmax[1][i]), fmaxf(pmax[2][i], pmax[3][i]));
        rowm[i] = m;
    }
    __syncthreads();
    float m = rowm[i];
    float s = 0.f;
    #pragma unroll
    for (int jj = 0; jj < 32; ++jj) s += expf(dv[jj] - m);
    psum[part][i] = s;
    __syncthreads();
    if (part == 0) {
        float tot = psum[0][i] + psum[1][i] + psum[2][i] + psum[3][i];
        float lse = m + logf(tot);
        lses[i] = lse;
        logits_ws[sbase + h * S + ti] = lse;
    }
    __syncthreads();
    float lse = lses[i];
    #pragma unroll
    for (int jj = 0; jj < 32; ++jj)
        Ds[i * 129 + part * 32 + jj] = expf(dv[jj] - lse);
    __syncthreads();

    // PV: thread (i, part) computes out[i][part*16 .. +16)
    int d0 = part << 4;
    float4 a0 = {0,0,0,0}, a1 = {0,0,0,0}, a2 = {0,0,0,0}, a3 = {0,0,0,0};
    for (int j = 0; j < 128; ++j) {
        float p = Ds[i * 129 + j];
        const float4* vr = (const float4*)(Vs + j * KSTR + d0);   // broadcast
        float4 v0 = vr[0], v1 = vr[1], v2 = vr[2], v3 = vr[3];
        a0.x += p * v0.x; a0.y += p * v0.y; a0.z += p * v0.z; a0.w += p * v0.w;
        a1.x += p * v1.x; a1.y += p * v1.y; a1.z += p * v1.z; a1.w += p * v1.w;
        a2.x += p * v2.x; a2.y += p * v2.y; a2.z += p * v2.z; a2.w += p * v2.w;
        a3.x += p * v3.x; a3.y += p * v3.y; a3.z += p * v3.z; a3.w += p * v3.w;
    }
    float* op = o_ws + ((size_t)(sbase + h * S + ti)) * D + d0;
    ((float4*)op)[0] = a0; ((float4*)op)[1] = a1;
    ((float4*)op)[2] = a2; ((float4*)op)[3] = a3;
}

// ---------------------------------------------------------------------------
// Kernel 4: combine hash rounds with softmax(logits) weights.
// grid: B*S*16/256 blocks; thread = (token, d4).
// ---------------------------------------------------------------------------
__global__ __launch_bounds__(256) void combine_kernel(
    const float* __restrict__ o_ws, const float* __restrict__ logits_ws,
    float* __restrict__ out)
{
    int gid = blockIdx.x * 256 + threadIdx.x;
    int token = gid >> 4;          // b*S + t
    int d4 = gid & 15;
    int b = token >> 12;
    int t = token & (S - 1);
    int base = b * (NH * S) + t;

    float l[8];
    #pragma unroll
    for (int hh = 0; hh < 8; ++hh) l[hh] = logits_ws[base + hh * S];
    float m = l[0];
    #pragma unroll
    for (int hh = 1; hh < 8; ++hh) m = fmaxf(m, l[hh]);
    float w[8]; float ssum = 0.f;
    #pragma unroll
    for (int hh = 0; hh < 8; ++hh) { w[hh] = expf(l[hh] - m); ssum += w[hh]; }
    float inv = 1.0f / ssum;

    float4 acc = {0,0,0,0};
    #pragma unroll
    for (int hh = 0; hh < 8; ++hh) {
        const float4 ov = ((const float4*)o_ws)[(size_t)(base + hh * S) * 16 + d4];
        float wh = w[hh] * inv;
        acc.x += wh * ov.x; acc.y += wh * ov.y; acc.z += wh * ov.z; acc.w += wh * ov.w;
    }
    ((float4*)out)[(size_t)token * 16 + d4] = acc;
}

// ---------------------------------------------------------------------------
extern "C" void kernel_launch(void* const* d_in, const int* in_sizes, int n_in,
                              void* d_out, int out_size, void* d_ws, size_t ws_size,
                              hipStream_t stream) {
    const float* qk  = (const float*)d_in[0];
    const float* v   = (const float*)d_in[1];
    const float* rot = (const float*)d_in[2];

    float* out         = (float*)d_out;                 // [B,S,D] = 4194304 floats
    float* out_buckets = out + (size_t)B * S * D;       // [B, NH*S] = 524288 floats

    int*   bucket_ws = (int*)d_ws;                      // 524288 ints
    int*   st_ws     = bucket_ws + (size_t)B * NH * S;  // 524288 ints
    float* logits_ws = (float*)(st_ws + (size_t)B * NH * S);    // 524288 floats
    float* o_ws      = logits_ws + (size_t)B * NH * S;  // 33554432 floats (128 MB)

    hash_kernel<<<B * NH * 4, 256, 0, stream>>>(qk, rot, out_buckets, bucket_ws);
    sort_kernel<<<B * NH, 64, 0, stream>>>(bucket_ws, st_ws);
    attn_kernel<<<B * CHUNKS, 256, 0, stream>>>(qk, v, st_ws, o_ws, logits_ws);
    combine_kernel<<<(B * S * 16) / 256, 256, 0, stream>>>(o_ws, logits_ws, out);
}

// Round 2
// 588.920 us; speedup vs baseline: 1.9493x; 1.9493x over previous
//
#include <hip/hip_runtime.h>
#include <hip/hip_bf16.h>
#include <math.h>

// Problem constants
#define B 16
#define S 4096
#define D 64
#define NH 8
#define NBUCK 64          // buckets per hash
#define CHUNKS 512        // chunks per batch (NH * NBUCK)
#define BS 64             // bucket/chunk size

typedef __attribute__((ext_vector_type(8))) short s8_t;   // 8 bf16 (4 VGPRs)
typedef __attribute__((ext_vector_type(4))) float f4_t;   // MFMA C/D

__device__ inline unsigned short bf16_rne(float x) {
    unsigned int u = __float_as_uint(x);
    u += 0x7fffu + ((u >> 16) & 1u);
    return (unsigned short)(u >> 16);
}
__device__ inline void split_bf16(float x, unsigned short& h, unsigned short& l) {
    h = bf16_rne(x);
    float hf = __uint_as_float(((unsigned int)h) << 16);
    l = bf16_rne(x - hf);
}

// ---------------------------------------------------------------------------
// Kernel 1: hashing (f64 accumulate for argmax stability vs np reference).
// ---------------------------------------------------------------------------
__global__ __launch_bounds__(256) void hash_kernel(
    const float* __restrict__ qk, const float* __restrict__ rot,
    float* __restrict__ out_buckets, int* __restrict__ bucket_ws)
{
    __shared__ double R[64 * 32];   // R[f*32+i], 16 KB
    int tid = threadIdx.x;
    int bid = blockIdx.x;
    int b   = bid >> 5;
    int h   = (bid >> 2) & 7;
    int qtr = bid & 3;

    for (int e = tid; e < 2048; e += 256) {
        int f = e >> 5, i = e & 31;
        R[e] = (double)rot[f * (NH * 32) + h * 32 + i];
    }
    __syncthreads();

    for (int k = 0; k < 4; ++k) {
        int t = qtr * 1024 + k * 256 + tid;
        const float4* rowp = (const float4*)(qk + ((size_t)b * S + t) * D);
        double acc[32];
        #pragma unroll
        for (int i = 0; i < 32; ++i) acc[i] = 0.0;

        for (int k2 = 0; k2 < 16; ++k2) {
            float4 x4 = rowp[k2];
            float xs[4] = {x4.x, x4.y, x4.z, x4.w};
            #pragma unroll
            for (int u = 0; u < 4; ++u) {
                double x = (double)xs[u];
                const double* Rr = &R[(k2 * 4 + u) * 32];
                #pragma unroll
                for (int i = 0; i < 32; ++i)
                    acc[i] = __fma_rn(x, Rr[i], acc[i]);
            }
        }
        double best = acc[0]; int bi = 0;
        double worst = acc[0]; int wi = 0;
        #pragma unroll
        for (int i = 1; i < 32; ++i) {
            if (acc[i] > best)  { best = acc[i]; bi = i; }
            if (acc[i] < worst) { worst = acc[i]; wi = i; }
        }
        int bucket = (-worst > best) ? (32 + wi) : bi;
        size_t idx = (size_t)(b * NH + h) * S + t;
        bucket_ws[idx] = bucket;
        out_buckets[idx] = (float)(bucket + h * NBUCK);
    }
}

// ---------------------------------------------------------------------------
// Kernel 2: stable counting sort per (b,h).
// ---------------------------------------------------------------------------
__global__ __launch_bounds__(64) void sort_kernel(
    const int* __restrict__ bucket_ws, int* __restrict__ st_ws)
{
    __shared__ int sb[S];
    __shared__ int cnt[64];
    int tid = threadIdx.x;
    int base = blockIdx.x * S;

    cnt[tid] = 0;
    __syncthreads();
    for (int t = tid; t < S; t += 64) {
        int vb = bucket_ws[base + t];
        sb[t] = vb;
        atomicAdd(&cnt[vb], 1);
    }
    __syncthreads();
    int myb = 0;
    for (int j = 0; j < 64; ++j) {
        int cj = cnt[j];
        if (j < tid) myb += cj;
    }
    int idx = myb;
    const int4* sb4 = (const int4*)sb;
    for (int t4 = 0; t4 < S / 4; ++t4) {
        int4 q = sb4[t4];
        int t = t4 * 4;
        if (q.x == tid) st_ws[base + idx++] = t;
        if (q.y == tid) st_ws[base + idx++] = t + 1;
        if (q.z == tid) st_ws[base + idx++] = t + 2;
        if (q.w == tid) st_ws[base + idx++] = t + 3;
    }
}

// ---------------------------------------------------------------------------
// Kernel 3: per-chunk attention via split-bf16 MFMA.
//   dots = (Khat_q . Khat_j) * nq * D^-0.5 with split-bf16 (hi+lo) MFMA
//   P, V also split-bf16; all accumulation f32 in MFMA.
// LDS layout (72704 B total -> 2 blocks/CU):
//   Kh[128][72 bf16] @0       (18432)   -- reused as Ph[64][136 bf16] after dots
//   Kl[128][72 bf16] @18432   (18432)   -- reused as Pl
//   Vth[64][136 bf16] @36864  (17408)   V transposed, hi
//   Vtl[64][136 bf16] @54272  (17408)   V transposed, lo
//   nrm[128] f32 @71680, tkx[128] int @72192
// ---------------------------------------------------------------------------
#define OFF_KH 0
#define OFF_KL 18432
#define OFF_VH 36864
#define OFF_VL 54272
#define OFF_NRM 71680
#define OFF_TKX 72192
#define LDS_TOT 72704
#define KSTRB 144     // Kh/Kl row stride bytes (72 bf16)
#define PSTRB 272     // P / Vt row stride bytes (136 bf16)

__global__ __launch_bounds__(256, 2) void attn_kernel(
    const float* __restrict__ qk, const float* __restrict__ v,
    const int* __restrict__ st_ws,
    float* __restrict__ o_ws, float* __restrict__ logits_ws)
{
    __shared__ char lds[LDS_TOT];
    float* nrm_s = (float*)(lds + OFF_NRM);
    int*   tkx   = (int*)(lds + OFF_TKX);

    int tid = threadIdx.x;
    int c = blockIdx.x & (CHUNKS - 1);
    int b = blockIdx.x >> 9;
    int h = c >> 6;
    int sbase = b * (NH * S);

    if (tid < 128) {
        int cc2 = (tid < 64) ? c : ((c + CHUNKS - 1) & (CHUNKS - 1));
        tkx[tid] = st_ws[sbase + cc2 * BS + (tid & 63)];
    }
    __syncthreads();

    // ---- stage: K normalized split-bf16 (row-major) + V split-bf16 (transposed)
    {
        int r = tid >> 1, half = tid & 1;
        int tok = tkx[r];
        const float4* qs = (const float4*)(qk + ((size_t)b * S + tok) * D) + half * 8;
        const float4* vs = (const float4*)(v  + ((size_t)b * S + tok) * D) + half * 8;
        float xq[32], xv[32];
        #pragma unroll
        for (int e4 = 0; e4 < 8; ++e4) {
            float4 a = qs[e4], w = vs[e4];
            xq[e4*4+0]=a.x; xq[e4*4+1]=a.y; xq[e4*4+2]=a.z; xq[e4*4+3]=a.w;
            xv[e4*4+0]=w.x; xv[e4*4+1]=w.y; xv[e4*4+2]=w.z; xv[e4*4+3]=w.w;
        }
        float ss = 0.f;
        #pragma unroll
        for (int e = 0; e < 32; ++e) ss += xq[e]*xq[e];
        ss += __shfl_xor(ss, 1);
        float nr = sqrtf(ss);
        float inv = 1.0f / fmaxf(nr, 1e-12f);
        if (!half) nrm_s[r] = nr;

        // K rows: pack split bf16 pairs, 16B stores
        unsigned int ph[16], pl[16];
        #pragma unroll
        for (int e = 0; e < 16; ++e) {
            unsigned short h0,l0,h1,l1;
            split_bf16(xq[2*e]   * inv, h0, l0);
            split_bf16(xq[2*e+1] * inv, h1, l1);
            ph[e] = (unsigned int)h0 | ((unsigned int)h1 << 16);
            pl[e] = (unsigned int)l0 | ((unsigned int)l1 << 16);
        }
        char* kb = lds + OFF_KH + r * KSTRB + half * 64;
        char* lb = lds + OFF_KL + r * KSTRB + half * 64;
        #pragma unroll
        for (int e4 = 0; e4 < 4; ++e4) {
            *(uint4*)(kb + e4*16) = make_uint4(ph[e4*4], ph[e4*4+1], ph[e4*4+2], ph[e4*4+3]);
            *(uint4*)(lb + e4*16) = make_uint4(pl[e4*4], pl[e4*4+1], pl[e4*4+2], pl[e4*4+3]);
        }

        // V transposed: Vt[dim][key], scatter b16 writes
        char* vhb = lds + OFF_VH + r * 2;
        char* vlb = lds + OFF_VL + r * 2;
        #pragma unroll
        for (int e = 0; e < 32; ++e) {
            int dd = half * 32 + e;
            unsigned short vh, vl;
            split_bf16(xv[e], vh, vl);
            *(unsigned short*)(vhb + dd * PSTRB) = vh;
            *(unsigned short*)(vlb + dd * PSTRB) = vl;
        }
    }
    __syncthreads();

    int wv   = tid >> 6;
    int lane = tid & 63;
    int quad = lane >> 4;
    int cc   = lane & 15;

    // ---- dots: QK^T via split-bf16 MFMA (A = query rows, B = key rows^T)
    const char* KH = lds + OFF_KH;
    const char* KL = lds + OFF_KL;
    int qrow = wv * 16 + cc;

    f4_t acc[8];
    #pragma unroll
    for (int t = 0; t < 8; ++t) acc[t] = (f4_t){0.f,0.f,0.f,0.f};

    #pragma unroll
    for (int kc = 0; kc < 2; ++kc) {
        int aoff = kc * 64 + quad * 16;
        s8_t ah = *(const s8_t*)(KH + qrow * KSTRB + aoff);
        s8_t al = *(const s8_t*)(KL + qrow * KSTRB + aoff);
        #pragma unroll
        for (int t = 0; t < 8; ++t) {
            int key = t * 16 + cc;
            s8_t bh = *(const s8_t*)(KH + key * KSTRB + aoff);
            s8_t bl = *(const s8_t*)(KL + key * KSTRB + aoff);
            acc[t] = __builtin_amdgcn_mfma_f32_16x16x32_bf16(ah, bh, acc[t], 0, 0, 0);
            acc[t] = __builtin_amdgcn_mfma_f32_16x16x32_bf16(ah, bl, acc[t], 0, 0, 0);
            acc[t] = __builtin_amdgcn_mfma_f32_16x16x32_bf16(al, bh, acc[t], 0, 0, 0);
        }
    }

    // ---- scale + self-mask + softmax (registers + shuffles)
    int tqi[4];
    float sc[4];
    #pragma unroll
    for (int g = 0; g < 4; ++g) {
        int q = wv * 16 + quad * 4 + g;
        tqi[g] = tkx[q];
        sc[g] = nrm_s[q] * 0.125f;
    }
    int tki[8];
    #pragma unroll
    for (int t = 0; t < 8; ++t) tki[t] = tkx[t * 16 + cc];

    #pragma unroll
    for (int t = 0; t < 8; ++t)
        #pragma unroll
        for (int g = 0; g < 4; ++g) {
            float d = acc[t][g] * sc[g];
            if (tqi[g] == tki[t]) d = -1e5f;
            acc[t][g] = d;
        }

    float mx[4];
    #pragma unroll
    for (int g = 0; g < 4; ++g) {
        float m = acc[0][g];
        #pragma unroll
        for (int t = 1; t < 8; ++t) m = fmaxf(m, acc[t][g]);
        mx[g] = m;
    }
    #pragma unroll
    for (int msk = 1; msk <= 8; msk <<= 1)
        #pragma unroll
        for (int g = 0; g < 4; ++g) mx[g] = fmaxf(mx[g], __shfl_xor(mx[g], msk, 64));

    float sm[4] = {0.f, 0.f, 0.f, 0.f};
    #pragma unroll
    for (int t = 0; t < 8; ++t)
        #pragma unroll
        for (int g = 0; g < 4; ++g) {
            float p = expf(acc[t][g] - mx[g]);
            acc[t][g] = p;
            sm[g] += p;
        }
    #pragma unroll
    for (int msk = 1; msk <= 8; msk <<= 1)
        #pragma unroll
        for (int g = 0; g < 4; ++g) sm[g] += __shfl_xor(sm[g], msk, 64);

    float pinv[4];
    #pragma unroll
    for (int g = 0; g < 4; ++g) pinv[g] = 1.0f / sm[g];

    if (cc == 0) {
        #pragma unroll
        for (int g = 0; g < 4; ++g)
            logits_ws[sbase + h * S + tqi[g]] = mx[g] + logf(sm[g]);
    }

    // ---- P -> split bf16 into LDS (overlaying Kh/Kl; all dots reads done)
    __syncthreads();
    char* PH = lds + OFF_KH;
    char* PL = lds + OFF_KL;
    #pragma unroll
    for (int t = 0; t < 8; ++t) {
        int key = t * 16 + cc;
        #pragma unroll
        for (int g = 0; g < 4; ++g) {
            int q = wv * 16 + quad * 4 + g;
            float p = acc[t][g] * pinv[g];
            unsigned short hh, ll;
            split_bf16(p, hh, ll);
            *(unsigned short*)(PH + q * PSTRB + key * 2) = hh;
            *(unsigned short*)(PL + q * PSTRB + key * 2) = ll;
        }
    }
    __syncthreads();

    // ---- PV via split-bf16 MFMA: A = P rows, B = Vt rows
    const char* VH = lds + OFF_VH;
    const char* VL = lds + OFF_VL;
    f4_t oacc[4];
    #pragma unroll
    for (int n = 0; n < 4; ++n) oacc[n] = (f4_t){0.f,0.f,0.f,0.f};

    #pragma unroll
    for (int kc = 0; kc < 4; ++kc) {
        int off = kc * 64 + quad * 16;
        s8_t pah = *(const s8_t*)(PH + (wv * 16 + cc) * PSTRB + off);
        s8_t pal = *(const s8_t*)(PL + (wv * 16 + cc) * PSTRB + off);
        #pragma unroll
        for (int n = 0; n < 4; ++n) {
            s8_t vh = *(const s8_t*)(VH + (n * 16 + cc) * PSTRB + off);
            s8_t vl = *(const s8_t*)(VL + (n * 16 + cc) * PSTRB + off);
            oacc[n] = __builtin_amdgcn_mfma_f32_16x16x32_bf16(pah, vh, oacc[n], 0, 0, 0);
            oacc[n] = __builtin_amdgcn_mfma_f32_16x16x32_bf16(pal, vh, oacc[n], 0, 0, 0);
            oacc[n] = __builtin_amdgcn_mfma_f32_16x16x32_bf16(pah, vl, oacc[n], 0, 0, 0);
        }
    }

    // ---- write O (scatter rows by token, coalesced 64B across cc)
    #pragma unroll
    for (int g = 0; g < 4; ++g) {
        float* op = o_ws + ((size_t)(sbase + h * S + tqi[g])) * D;
        #pragma unroll
        for (int n = 0; n < 4; ++n)
            op[n * 16 + cc] = oacc[n][g];
    }
}

// ---------------------------------------------------------------------------
// Kernel 4: combine hash rounds with softmax(logits) weights.
// ---------------------------------------------------------------------------
__global__ __launch_bounds__(256) void combine_kernel(
    const float* __restrict__ o_ws, const float* __restrict__ logits_ws,
    float* __restrict__ out)
{
    int gid = blockIdx.x * 256 + threadIdx.x;
    int token = gid >> 4;          // b*S + t
    int d4 = gid & 15;
    int b = token >> 12;
    int t = token & (S - 1);
    int base = b * (NH * S) + t;

    float l[8];
    #pragma unroll
    for (int hh = 0; hh < 8; ++hh) l[hh] = logits_ws[base + hh * S];
    float m = l[0];
    #pragma unroll
    for (int hh = 1; hh < 8; ++hh) m = fmaxf(m, l[hh]);
    float w[8]; float ssum = 0.f;
    #pragma unroll
    for (int hh = 0; hh < 8; ++hh) { w[hh] = expf(l[hh] - m); ssum += w[hh]; }
    float inv = 1.0f / ssum;

    float4 acc = {0,0,0,0};
    #pragma unroll
    for (int hh = 0; hh < 8; ++hh) {
        const float4 ov = ((const float4*)o_ws)[(size_t)(base + hh * S) * 16 + d4];
        float wh = w[hh] * inv;
        acc.x += wh * ov.x; acc.y += wh * ov.y; acc.z += wh * ov.z; acc.w += wh * ov.w;
    }
    ((float4*)out)[(size_t)token * 16 + d4] = acc;
}

// ---------------------------------------------------------------------------
extern "C" void kernel_launch(void* const* d_in, const int* in_sizes, int n_in,
                              void* d_out, int out_size, void* d_ws, size_t ws_size,
                              hipStream_t stream) {
    const float* qk  = (const float*)d_in[0];
    const float* v   = (const float*)d_in[1];
    const float* rot = (const float*)d_in[2];

    float* out         = (float*)d_out;
    float* out_buckets = out + (size_t)B * S * D;

    int*   bucket_ws = (int*)d_ws;
    int*   st_ws     = bucket_ws + (size_t)B * NH * S;
    float* logits_ws = (float*)(st_ws + (size_t)B * NH * S);
    float* o_ws      = logits_ws + (size_t)B * NH * S;

    hash_kernel<<<B * NH * 4, 256, 0, stream>>>(qk, rot, out_buckets, bucket_ws);
    sort_kernel<<<B * NH, 64, 0, stream>>>(bucket_ws, st_ws);
    attn_kernel<<<B * CHUNKS, 256, 0, stream>>>(qk, v, st_ws, o_ws, logits_ws);
    combine_kernel<<<(B * S * 16) / 256, 256, 0, stream>>>(o_ws, logits_ws, out);
}

// Round 3
// 399.671 us; speedup vs baseline: 2.8723x; 1.4735x over previous
//
#include <hip/hip_runtime.h>
#include <hip/hip_bf16.h>
#include <math.h>

// Problem constants
#define B 16
#define S 4096
#define D 64
#define NH 8
#define NBUCK 64          // buckets per hash
#define CHUNKS 512        // chunks per batch (NH * NBUCK)
#define BS 64             // bucket/chunk size

typedef __attribute__((ext_vector_type(8))) short s8_t;   // 8 bf16 (4 VGPRs)
typedef __attribute__((ext_vector_type(4))) float f4_t;   // MFMA C/D

__device__ inline unsigned short bf16_rne(float x) {
    unsigned int u = __float_as_uint(x);
    u += 0x7fffu + ((u >> 16) & 1u);
    return (unsigned short)(u >> 16);
}
__device__ inline void split_bf16(float x, unsigned short& h, unsigned short& l) {
    h = bf16_rne(x);
    float hf = __uint_as_float(((unsigned int)h) << 16);
    l = bf16_rne(x - hf);
}

// ---------------------------------------------------------------------------
// Kernel 1: hashing (f64 accumulate for argmax stability vs np reference).
// ---------------------------------------------------------------------------
__global__ __launch_bounds__(256) void hash_kernel(
    const float* __restrict__ qk, const float* __restrict__ rot,
    float* __restrict__ out_buckets, int* __restrict__ bucket_ws)
{
    __shared__ double R[64 * 32];   // R[f*32+i], 16 KB
    int tid = threadIdx.x;
    int bid = blockIdx.x;
    int b   = bid >> 5;
    int h   = (bid >> 2) & 7;
    int qtr = bid & 3;

    for (int e = tid; e < 2048; e += 256) {
        int f = e >> 5, i = e & 31;
        R[e] = (double)rot[f * (NH * 32) + h * 32 + i];
    }
    __syncthreads();

    for (int k = 0; k < 4; ++k) {
        int t = qtr * 1024 + k * 256 + tid;
        const float4* rowp = (const float4*)(qk + ((size_t)b * S + t) * D);
        double acc[32];
        #pragma unroll
        for (int i = 0; i < 32; ++i) acc[i] = 0.0;

        for (int k2 = 0; k2 < 16; ++k2) {
            float4 x4 = rowp[k2];
            float xs[4] = {x4.x, x4.y, x4.z, x4.w};
            #pragma unroll
            for (int u = 0; u < 4; ++u) {
                double x = (double)xs[u];
                const double* Rr = &R[(k2 * 4 + u) * 32];
                #pragma unroll
                for (int i = 0; i < 32; ++i)
                    acc[i] = __fma_rn(x, Rr[i], acc[i]);
            }
        }
        double best = acc[0]; int bi = 0;
        double worst = acc[0]; int wi = 0;
        #pragma unroll
        for (int i = 1; i < 32; ++i) {
            if (acc[i] > best)  { best = acc[i]; bi = i; }
            if (acc[i] < worst) { worst = acc[i]; wi = i; }
        }
        int bucket = (-worst > best) ? (32 + wi) : bi;
        size_t idx = (size_t)(b * NH + h) * S + t;
        bucket_ws[idx] = bucket;
        out_buckets[idx] = (float)(bucket + h * NBUCK);
    }
}

// ---------------------------------------------------------------------------
// Kernel 2: parallel stable counting sort per (b,h). 256 threads (4 waves).
// Phase 1: stage buckets to LDS + per-wave histograms (LDS atomics).
// Phase 2: bucket exclusive prefix (shuffle scan) + per-wave start offsets.
// Phase 3: each wave scans its quarter in 64-token groups; within-group
//          same-bucket rank via 6-ballot match mask; leaders bump offsets.
// ---------------------------------------------------------------------------
__global__ __launch_bounds__(256) void sort_kernel(
    const int* __restrict__ bucket_ws, int* __restrict__ st_ws)
{
    __shared__ int sb[S];          // staged buckets (16 KB)
    __shared__ int hist[4][64];    // per-wave histograms
    __shared__ int bpref[64];      // exclusive prefix over buckets (totals)
    __shared__ int woff[4][64];    // per-wave running offsets per bucket

    int tid  = threadIdx.x;
    int wv   = tid >> 6;
    int lane = tid & 63;
    int base = blockIdx.x * S;     // blockIdx.x == b*NH + h

    hist[wv][lane] = 0;
    __syncthreads();

    // Phase 1: stage + per-wave histogram (wave w owns tokens [w*1024, +1024))
    int qbase = wv * 1024;
    #pragma unroll
    for (int i = 0; i < 16; ++i) {
        int t = qbase + i * 64 + lane;
        int v = bucket_ws[base + t];
        sb[t] = v;
        atomicAdd(&hist[wv][v], 1);
    }
    __syncthreads();

    // Phase 2: totals -> exclusive prefix over buckets (wave 0), then woff
    if (wv == 0) {
        int total = hist[0][lane] + hist[1][lane] + hist[2][lane] + hist[3][lane];
        int x = total;
        #pragma unroll
        for (int off = 1; off < 64; off <<= 1) {
            int y = __shfl_up(x, off, 64);
            if (lane >= off) x += y;
        }
        bpref[lane] = x - total;   // exclusive prefix
    }
    __syncthreads();
    {
        int o = bpref[lane];
        for (int w2 = 0; w2 < 4; ++w2) {
            if (w2 < wv) o += hist[w2][lane];
        }
        woff[wv][lane] = o;
    }
    __syncthreads();

    // Phase 3: 16 groups of 64 tokens per wave, in ascending t order
    for (int g = 0; g < 16; ++g) {
        int t = qbase + g * 64 + lane;
        int v = sb[t];

        // match mask: lanes in this group with the same bucket
        unsigned long long m = ~0ULL;
        #pragma unroll
        for (int bit = 0; bit < 6; ++bit) {
            unsigned long long bm = __ballot((v >> bit) & 1);
            m &= ((v >> bit) & 1) ? bm : ~bm;
        }
        unsigned long long below = (lane == 63) ? ~0ULL >> 1
                                 : ((1ULL << lane) - 1ULL);
        int rank = __popcll(m & below);
        int cnt  = __popcll(m);

        int pos = woff[wv][v] + rank;
        st_ws[base + pos] = t;

        // leader (lowest lane of each match group) bumps the running offset
        if ((m & below) == 0ULL)
            woff[wv][v] += cnt;
        __builtin_amdgcn_s_waitcnt(0);   // ensure LDS update ordering in-wave
    }
}

// ---------------------------------------------------------------------------
// Kernel 3: per-chunk attention via split-bf16 MFMA.
// ---------------------------------------------------------------------------
#define OFF_KH 0
#define OFF_KL 18432
#define OFF_VH 36864
#define OFF_VL 54272
#define OFF_NRM 71680
#define OFF_TKX 72192
#define LDS_TOT 72704
#define KSTRB 144     // Kh/Kl row stride bytes (72 bf16)
#define PSTRB 272     // P / Vt row stride bytes (136 bf16)

__global__ __launch_bounds__(256, 2) void attn_kernel(
    const float* __restrict__ qk, const float* __restrict__ v,
    const int* __restrict__ st_ws,
    float* __restrict__ o_ws, float* __restrict__ logits_ws)
{
    __shared__ char lds[LDS_TOT];
    float* nrm_s = (float*)(lds + OFF_NRM);
    int*   tkx   = (int*)(lds + OFF_TKX);

    int tid = threadIdx.x;
    int c = blockIdx.x & (CHUNKS - 1);
    int b = blockIdx.x >> 9;
    int h = c >> 6;
    int sbase = b * (NH * S);

    if (tid < 128) {
        int cc2 = (tid < 64) ? c : ((c + CHUNKS - 1) & (CHUNKS - 1));
        tkx[tid] = st_ws[sbase + cc2 * BS + (tid & 63)];
    }
    __syncthreads();

    // ---- stage: K normalized split-bf16 (row-major) + V split-bf16 (transposed)
    {
        int r = tid >> 1, half = tid & 1;
        int tok = tkx[r];
        const float4* qs = (const float4*)(qk + ((size_t)b * S + tok) * D) + half * 8;
        const float4* vs = (const float4*)(v  + ((size_t)b * S + tok) * D) + half * 8;
        float xq[32], xv[32];
        #pragma unroll
        for (int e4 = 0; e4 < 8; ++e4) {
            float4 a = qs[e4], w = vs[e4];
            xq[e4*4+0]=a.x; xq[e4*4+1]=a.y; xq[e4*4+2]=a.z; xq[e4*4+3]=a.w;
            xv[e4*4+0]=w.x; xv[e4*4+1]=w.y; xv[e4*4+2]=w.z; xv[e4*4+3]=w.w;
        }
        float ss = 0.f;
        #pragma unroll
        for (int e = 0; e < 32; ++e) ss += xq[e]*xq[e];
        ss += __shfl_xor(ss, 1);
        float nr = sqrtf(ss);
        float inv = 1.0f / fmaxf(nr, 1e-12f);
        if (!half) nrm_s[r] = nr;

        unsigned int ph[16], pl[16];
        #pragma unroll
        for (int e = 0; e < 16; ++e) {
            unsigned short h0,l0,h1,l1;
            split_bf16(xq[2*e]   * inv, h0, l0);
            split_bf16(xq[2*e+1] * inv, h1, l1);
            ph[e] = (unsigned int)h0 | ((unsigned int)h1 << 16);
            pl[e] = (unsigned int)l0 | ((unsigned int)l1 << 16);
        }
        char* kb = lds + OFF_KH + r * KSTRB + half * 64;
        char* lb = lds + OFF_KL + r * KSTRB + half * 64;
        #pragma unroll
        for (int e4 = 0; e4 < 4; ++e4) {
            *(uint4*)(kb + e4*16) = make_uint4(ph[e4*4], ph[e4*4+1], ph[e4*4+2], ph[e4*4+3]);
            *(uint4*)(lb + e4*16) = make_uint4(pl[e4*4], pl[e4*4+1], pl[e4*4+2], pl[e4*4+3]);
        }

        char* vhb = lds + OFF_VH + r * 2;
        char* vlb = lds + OFF_VL + r * 2;
        #pragma unroll
        for (int e = 0; e < 32; ++e) {
            int dd = half * 32 + e;
            unsigned short vh, vl;
            split_bf16(xv[e], vh, vl);
            *(unsigned short*)(vhb + dd * PSTRB) = vh;
            *(unsigned short*)(vlb + dd * PSTRB) = vl;
        }
    }
    __syncthreads();

    int wv   = tid >> 6;
    int lane = tid & 63;
    int quad = lane >> 4;
    int cc   = lane & 15;

    // ---- dots: QK^T via split-bf16 MFMA
    const char* KH = lds + OFF_KH;
    const char* KL = lds + OFF_KL;
    int qrow = wv * 16 + cc;

    f4_t acc[8];
    #pragma unroll
    for (int t = 0; t < 8; ++t) acc[t] = (f4_t){0.f,0.f,0.f,0.f};

    #pragma unroll
    for (int kc = 0; kc < 2; ++kc) {
        int aoff = kc * 64 + quad * 16;
        s8_t ah = *(const s8_t*)(KH + qrow * KSTRB + aoff);
        s8_t al = *(const s8_t*)(KL + qrow * KSTRB + aoff);
        #pragma unroll
        for (int t = 0; t < 8; ++t) {
            int key = t * 16 + cc;
            s8_t bh = *(const s8_t*)(KH + key * KSTRB + aoff);
            s8_t bl = *(const s8_t*)(KL + key * KSTRB + aoff);
            acc[t] = __builtin_amdgcn_mfma_f32_16x16x32_bf16(ah, bh, acc[t], 0, 0, 0);
            acc[t] = __builtin_amdgcn_mfma_f32_16x16x32_bf16(ah, bl, acc[t], 0, 0, 0);
            acc[t] = __builtin_amdgcn_mfma_f32_16x16x32_bf16(al, bh, acc[t], 0, 0, 0);
        }
    }

    // ---- scale + self-mask + softmax
    int tqi[4];
    float sc[4];
    #pragma unroll
    for (int g = 0; g < 4; ++g) {
        int q = wv * 16 + quad * 4 + g;
        tqi[g] = tkx[q];
        sc[g] = nrm_s[q] * 0.125f;
    }
    int tki[8];
    #pragma unroll
    for (int t = 0; t < 8; ++t) tki[t] = tkx[t * 16 + cc];

    #pragma unroll
    for (int t = 0; t < 8; ++t)
        #pragma unroll
        for (int g = 0; g < 4; ++g) {
            float d = acc[t][g] * sc[g];
            if (tqi[g] == tki[t]) d = -1e5f;
            acc[t][g] = d;
        }

    float mx[4];
    #pragma unroll
    for (int g = 0; g < 4; ++g) {
        float m = acc[0][g];
        #pragma unroll
        for (int t = 1; t < 8; ++t) m = fmaxf(m, acc[t][g]);
        mx[g] = m;
    }
    #pragma unroll
    for (int msk = 1; msk <= 8; msk <<= 1)
        #pragma unroll
        for (int g = 0; g < 4; ++g) mx[g] = fmaxf(mx[g], __shfl_xor(mx[g], msk, 64));

    float sm[4] = {0.f, 0.f, 0.f, 0.f};
    #pragma unroll
    for (int t = 0; t < 8; ++t)
        #pragma unroll
        for (int g = 0; g < 4; ++g) {
            float p = expf(acc[t][g] - mx[g]);
            acc[t][g] = p;
            sm[g] += p;
        }
    #pragma unroll
    for (int msk = 1; msk <= 8; msk <<= 1)
        #pragma unroll
        for (int g = 0; g < 4; ++g) sm[g] += __shfl_xor(sm[g], msk, 64);

    float pinv[4];
    #pragma unroll
    for (int g = 0; g < 4; ++g) pinv[g] = 1.0f / sm[g];

    if (cc == 0) {
        #pragma unroll
        for (int g = 0; g < 4; ++g)
            logits_ws[sbase + h * S + tqi[g]] = mx[g] + logf(sm[g]);
    }

    // ---- P -> split bf16 into LDS (overlaying Kh/Kl)
    __syncthreads();
    char* PH = lds + OFF_KH;
    char* PL = lds + OFF_KL;
    #pragma unroll
    for (int t = 0; t < 8; ++t) {
        int key = t * 16 + cc;
        #pragma unroll
        for (int g = 0; g < 4; ++g) {
            int q = wv * 16 + quad * 4 + g;
            float p = acc[t][g] * pinv[g];
            unsigned short hh, ll;
            split_bf16(p, hh, ll);
            *(unsigned short*)(PH + q * PSTRB + key * 2) = hh;
            *(unsigned short*)(PL + q * PSTRB + key * 2) = ll;
        }
    }
    __syncthreads();

    // ---- PV via split-bf16 MFMA
    const char* VH = lds + OFF_VH;
    const char* VL = lds + OFF_VL;
    f4_t oacc[4];
    #pragma unroll
    for (int n = 0; n < 4; ++n) oacc[n] = (f4_t){0.f,0.f,0.f,0.f};

    #pragma unroll
    for (int kc = 0; kc < 4; ++kc) {
        int off = kc * 64 + quad * 16;
        s8_t pah = *(const s8_t*)(PH + (wv * 16 + cc) * PSTRB + off);
        s8_t pal = *(const s8_t*)(PL + (wv * 16 + cc) * PSTRB + off);
        #pragma unroll
        for (int n = 0; n < 4; ++n) {
            s8_t vh = *(const s8_t*)(VH + (n * 16 + cc) * PSTRB + off);
            s8_t vl = *(const s8_t*)(VL + (n * 16 + cc) * PSTRB + off);
            oacc[n] = __builtin_amdgcn_mfma_f32_16x16x32_bf16(pah, vh, oacc[n], 0, 0, 0);
            oacc[n] = __builtin_amdgcn_mfma_f32_16x16x32_bf16(pal, vh, oacc[n], 0, 0, 0);
            oacc[n] = __builtin_amdgcn_mfma_f32_16x16x32_bf16(pah, vl, oacc[n], 0, 0, 0);
        }
    }

    // ---- write O
    #pragma unroll
    for (int g = 0; g < 4; ++g) {
        float* op = o_ws + ((size_t)(sbase + h * S + tqi[g])) * D;
        #pragma unroll
        for (int n = 0; n < 4; ++n)
            op[n * 16 + cc] = oacc[n][g];
    }
}

// ---------------------------------------------------------------------------
// Kernel 4: combine hash rounds with softmax(logits) weights.
// ---------------------------------------------------------------------------
__global__ __launch_bounds__(256) void combine_kernel(
    const float* __restrict__ o_ws, const float* __restrict__ logits_ws,
    float* __restrict__ out)
{
    int gid = blockIdx.x * 256 + threadIdx.x;
    int token = gid >> 4;          // b*S + t
    int d4 = gid & 15;
    int b = token >> 12;
    int t = token & (S - 1);
    int base = b * (NH * S) + t;

    float l[8];
    #pragma unroll
    for (int hh = 0; hh < 8; ++hh) l[hh] = logits_ws[base + hh * S];
    float m = l[0];
    #pragma unroll
    for (int hh = 1; hh < 8; ++hh) m = fmaxf(m, l[hh]);
    float w[8]; float ssum = 0.f;
    #pragma unroll
    for (int hh = 0; hh < 8; ++hh) { w[hh] = expf(l[hh] - m); ssum += w[hh]; }
    float inv = 1.0f / ssum;

    float4 acc = {0,0,0,0};
    #pragma unroll
    for (int hh = 0; hh < 8; ++hh) {
        const float4 ov = ((const float4*)o_ws)[(size_t)(base + hh * S) * 16 + d4];
        float wh = w[hh] * inv;
        acc.x += wh * ov.x; acc.y += wh * ov.y; acc.z += wh * ov.z; acc.w += wh * ov.w;
    }
    ((float4*)out)[(size_t)token * 16 + d4] = acc;
}

// ---------------------------------------------------------------------------
extern "C" void kernel_launch(void* const* d_in, const int* in_sizes, int n_in,
                              void* d_out, int out_size, void* d_ws, size_t ws_size,
                              hipStream_t stream) {
    const float* qk  = (const float*)d_in[0];
    const float* v   = (const float*)d_in[1];
    const float* rot = (const float*)d_in[2];

    float* out         = (float*)d_out;
    float* out_buckets = out + (size_t)B * S * D;

    int*   bucket_ws = (int*)d_ws;
    int*   st_ws     = bucket_ws + (size_t)B * NH * S;
    float* logits_ws = (float*)(st_ws + (size_t)B * NH * S);
    float* o_ws      = logits_ws + (size_t)B * NH * S;

    hash_kernel<<<B * NH * 4, 256, 0, stream>>>(qk, rot, out_buckets, bucket_ws);
    sort_kernel<<<B * NH, 256, 0, stream>>>(bucket_ws, st_ws);
    attn_kernel<<<B * CHUNKS, 256, 0, stream>>>(qk, v, st_ws, o_ws, logits_ws);
    combine_kernel<<<(B * S * 16) / 256, 256, 0, stream>>>(o_ws, logits_ws, out);
}

// Round 4
// 330.525 us; speedup vs baseline: 3.4732x; 1.2092x over previous
//
#include <hip/hip_runtime.h>
#include <hip/hip_bf16.h>
#include <math.h>

// Problem constants
#define B 16
#define S 4096
#define D 64
#define NH 8
#define NBUCK 64          // buckets per hash
#define CHUNKS 512        // chunks per batch (NH * NBUCK)
#define BS 64             // bucket/chunk size

typedef __attribute__((ext_vector_type(8))) short s8_t;   // 8 bf16 (4 VGPRs)
typedef __attribute__((ext_vector_type(4))) float f4_t;   // MFMA C/D
typedef __attribute__((ext_vector_type(4))) unsigned int u4_t;

__device__ inline unsigned short bf16_rne(float x) {
    unsigned int u = __float_as_uint(x);
    u += 0x7fffu + ((u >> 16) & 1u);
    return (unsigned short)(u >> 16);
}
__device__ inline void split_bf16(float x, unsigned short& h, unsigned short& l) {
    h = bf16_rne(x);
    float hf = __uint_as_float(((unsigned int)h) << 16);
    l = bf16_rne(x - hf);
}

// build s8_t bf16 fragment from 8 packed (hi|lo<<16) dwords via v_perm
__device__ inline s8_t mk_frag(uint4 ra, uint4 rb, unsigned int sel) {
    union { u4_t u; s8_t s; } c;
    c.u = (u4_t){ __builtin_amdgcn_perm(ra.y, ra.x, sel),
                  __builtin_amdgcn_perm(ra.w, ra.z, sel),
                  __builtin_amdgcn_perm(rb.y, rb.x, sel),
                  __builtin_amdgcn_perm(rb.w, rb.z, sel) };
    return c.s;
}
#define SEL_HI 0x05040100u
#define SEL_LO 0x07060302u

// ---------------------------------------------------------------------------
// Kernel 1: hashing (f64, register-blocked: 4 tokens/lane x 16 outputs x 2
// passes). FMA order per (i,f) identical to the naive version -> bit-identical
// buckets. LDS R-reads amortized 4 tokens per b128 broadcast.
// ---------------------------------------------------------------------------
__global__ __launch_bounds__(256) void hash_kernel(
    const float* __restrict__ qk, const float* __restrict__ rot,
    float* __restrict__ out_buckets, int* __restrict__ bucket_ws)
{
    __shared__ double R[64 * 32];   // R[f*32+i], 16 KB
    int tid = threadIdx.x;
    int bid = blockIdx.x;
    int b   = bid >> 5;
    int h   = (bid >> 2) & 7;
    int qtr = bid & 3;

    for (int e = tid; e < 2048; e += 256) {
        int f = e >> 5, i = e & 31;
        R[e] = (double)rot[f * (NH * 32) + h * 32 + i];
    }
    __syncthreads();

    const float4* rowp[4];
    #pragma unroll
    for (int j = 0; j < 4; ++j) {
        int t = qtr * 1024 + j * 256 + tid;
        rowp[j] = (const float4*)(qk + ((size_t)b * S + t) * D);
    }

    double bestv[4], worstv[4];
    int bi[4], wi[4];

    for (int p = 0; p < 2; ++p) {
        double acc[64];   // acc[i*4+j], i in 0..15 (outputs p*16+i)
        #pragma unroll
        for (int e = 0; e < 64; ++e) acc[e] = 0.0;

        for (int fc = 0; fc < 16; ++fc) {
            float xf[4][4];
            #pragma unroll
            for (int j = 0; j < 4; ++j) {
                float4 x4 = rowp[j][fc];
                xf[j][0] = x4.x; xf[j][1] = x4.y; xf[j][2] = x4.z; xf[j][3] = x4.w;
            }
            #pragma unroll
            for (int u = 0; u < 4; ++u) {
                int f = fc * 4 + u;
                const double2* Rr = (const double2*)&R[f * 32 + p * 16];
                double xd[4];
                #pragma unroll
                for (int j = 0; j < 4; ++j) xd[j] = (double)xf[j][u];
                #pragma unroll
                for (int ii = 0; ii < 8; ++ii) {
                    double2 r2 = Rr[ii];
                    #pragma unroll
                    for (int j = 0; j < 4; ++j) {
                        acc[(2*ii)*4 + j]   = __fma_rn(xd[j], r2.x, acc[(2*ii)*4 + j]);
                        acc[(2*ii+1)*4 + j] = __fma_rn(xd[j], r2.y, acc[(2*ii+1)*4 + j]);
                    }
                }
            }
        }
        // merge extrema (scan order = ascending global index, strict compares)
        #pragma unroll
        for (int i = 0; i < 16; ++i) {
            int gi = p * 16 + i;
            #pragma unroll
            for (int j = 0; j < 4; ++j) {
                double vv = acc[i*4 + j];
                if (p == 0 && i == 0) {
                    bestv[j] = vv; bi[j] = 0; worstv[j] = vv; wi[j] = 0;
                } else {
                    if (vv > bestv[j])  { bestv[j] = vv; bi[j] = gi; }
                    if (vv < worstv[j]) { worstv[j] = vv; wi[j] = gi; }
                }
            }
        }
    }

    #pragma unroll
    for (int j = 0; j < 4; ++j) {
        int t = qtr * 1024 + j * 256 + tid;
        int bucket = (-worstv[j] > bestv[j]) ? (32 + wi[j]) : bi[j];
        size_t idx = (size_t)(b * NH + h) * S + t;
        bucket_ws[idx] = bucket;
        out_buckets[idx] = (float)(bucket + h * NBUCK);
    }
}

// ---------------------------------------------------------------------------
// Kernel 2: parallel stable counting sort per (b,h). 256 threads (4 waves).
// ---------------------------------------------------------------------------
__global__ __launch_bounds__(256) void sort_kernel(
    const int* __restrict__ bucket_ws, int* __restrict__ st_ws)
{
    __shared__ int sb[S];
    __shared__ int hist[4][64];
    __shared__ int bpref[64];
    __shared__ int woff[4][64];

    int tid  = threadIdx.x;
    int wv   = tid >> 6;
    int lane = tid & 63;
    int base = blockIdx.x * S;

    hist[wv][lane] = 0;
    __syncthreads();

    int qbase = wv * 1024;
    #pragma unroll
    for (int i = 0; i < 16; ++i) {
        int t = qbase + i * 64 + lane;
        int v = bucket_ws[base + t];
        sb[t] = v;
        atomicAdd(&hist[wv][v], 1);
    }
    __syncthreads();

    if (wv == 0) {
        int total = hist[0][lane] + hist[1][lane] + hist[2][lane] + hist[3][lane];
        int x = total;
        #pragma unroll
        for (int off = 1; off < 64; off <<= 1) {
            int y = __shfl_up(x, off, 64);
            if (lane >= off) x += y;
        }
        bpref[lane] = x - total;
    }
    __syncthreads();
    {
        int o = bpref[lane];
        for (int w2 = 0; w2 < 4; ++w2) {
            if (w2 < wv) o += hist[w2][lane];
        }
        woff[wv][lane] = o;
    }
    __syncthreads();

    for (int g = 0; g < 16; ++g) {
        int t = qbase + g * 64 + lane;
        int v = sb[t];

        unsigned long long m = ~0ULL;
        #pragma unroll
        for (int bit = 0; bit < 6; ++bit) {
            unsigned long long bm = __ballot((v >> bit) & 1);
            m &= ((v >> bit) & 1) ? bm : ~bm;
        }
        unsigned long long below = (lane == 63) ? ~0ULL >> 1
                                 : ((1ULL << lane) - 1ULL);
        int rank = __popcll(m & below);
        int cnt  = __popcll(m);

        int pos = woff[wv][v] + rank;
        st_ws[base + pos] = t;

        if ((m & below) == 0ULL)
            woff[wv][v] += cnt;
        __builtin_amdgcn_s_waitcnt(0);
    }
}

// ---------------------------------------------------------------------------
// Kernel 3: per-chunk attention via split-bf16 MFMA.
// LDS layout (71680 B -> 2 blocks/CU):
//   KH[128][72 bf16] @0      (18432)  -- overlaid by PHL[64][132 dw] after dots
//   KL[128][72 bf16] @18432  (18432)
//   VHL[64][132 dw]  @36864  (33792)  V transposed, (hi|lo<<16) packed dwords
//   nrm @70656, tkx @71168
// ---------------------------------------------------------------------------
#define OFF_KH 0
#define OFF_KL 18432
#define OFF_VHL 36864
#define OFF_NRM 70656
#define OFF_TKX 71168
#define LDS_TOT 71680
#define KSTRB 144     // Kh/Kl row stride bytes (72 bf16)
#define PVSTRD 132    // P / Vt packed row stride (dwords)

__global__ __launch_bounds__(256, 2) void attn_kernel(
    const float* __restrict__ qk, const float* __restrict__ v,
    const int* __restrict__ st_ws,
    float* __restrict__ o_ws, float* __restrict__ logits_ws)
{
    __shared__ char lds[LDS_TOT];
    float* nrm_s = (float*)(lds + OFF_NRM);
    int*   tkx   = (int*)(lds + OFF_TKX);
    unsigned int* VHLd = (unsigned int*)(lds + OFF_VHL);
    unsigned int* PHLd = (unsigned int*)lds;          // overlays KH/KL

    int tid = threadIdx.x;
    int c = blockIdx.x & (CHUNKS - 1);
    int b = blockIdx.x >> 9;
    int h = c >> 6;
    int sbase = b * (NH * S);

    if (tid < 128) {
        int cc2 = (tid < 64) ? c : ((c + CHUNKS - 1) & (CHUNKS - 1));
        tkx[tid] = st_ws[sbase + cc2 * BS + (tid & 63)];
    }
    __syncthreads();

    // ---- stage K (normalized, split hi/lo rows) + V (transposed, packed)
    {
        int r = tid >> 1, half = tid & 1;
        int tok = tkx[r];
        const float4* qs = (const float4*)(qk + ((size_t)b * S + tok) * D) + half * 8;
        const float4* vs = (const float4*)(v  + ((size_t)b * S + tok) * D) + half * 8;
        float xq[32], xv[32];
        #pragma unroll
        for (int e4 = 0; e4 < 8; ++e4) {
            float4 a = qs[e4], w = vs[e4];
            xq[e4*4+0]=a.x; xq[e4*4+1]=a.y; xq[e4*4+2]=a.z; xq[e4*4+3]=a.w;
            xv[e4*4+0]=w.x; xv[e4*4+1]=w.y; xv[e4*4+2]=w.z; xv[e4*4+3]=w.w;
        }
        float ss = 0.f;
        #pragma unroll
        for (int e = 0; e < 32; ++e) ss += xq[e]*xq[e];
        ss += __shfl_xor(ss, 1);
        float nr = sqrtf(ss);
        float inv = 1.0f / fmaxf(nr, 1e-12f);
        if (!half) nrm_s[r] = nr;

        unsigned int ph[16], pl[16];
        #pragma unroll
        for (int e = 0; e < 16; ++e) {
            unsigned short h0,l0,h1,l1;
            split_bf16(xq[2*e]   * inv, h0, l0);
            split_bf16(xq[2*e+1] * inv, h1, l1);
            ph[e] = (unsigned int)h0 | ((unsigned int)h1 << 16);
            pl[e] = (unsigned int)l0 | ((unsigned int)l1 << 16);
        }
        char* kb = lds + OFF_KH + r * KSTRB + half * 64;
        char* lb = lds + OFF_KL + r * KSTRB + half * 64;
        #pragma unroll
        for (int e4 = 0; e4 < 4; ++e4) {
            *(uint4*)(kb + e4*16) = make_uint4(ph[e4*4], ph[e4*4+1], ph[e4*4+2], ph[e4*4+3]);
            *(uint4*)(lb + e4*16) = make_uint4(pl[e4*4], pl[e4*4+1], pl[e4*4+2], pl[e4*4+3]);
        }

        // V transposed, packed (hi|lo<<16) dword per element
        #pragma unroll
        for (int e = 0; e < 32; ++e) {
            int dd = half * 32 + e;
            unsigned short vh, vl;
            split_bf16(xv[e], vh, vl);
            VHLd[dd * PVSTRD + r] = (unsigned int)vh | ((unsigned int)vl << 16);
        }
    }
    __syncthreads();

    int wv   = tid >> 6;
    int lane = tid & 63;
    int quad = lane >> 4;
    int cc   = lane & 15;

    // ---- dots: QK^T via split-bf16 MFMA
    const char* KH = lds + OFF_KH;
    const char* KL = lds + OFF_KL;
    int qrow = wv * 16 + cc;

    f4_t acc[8];
    #pragma unroll
    for (int t = 0; t < 8; ++t) acc[t] = (f4_t){0.f,0.f,0.f,0.f};

    #pragma unroll
    for (int kc = 0; kc < 2; ++kc) {
        int aoff = kc * 64 + quad * 16;
        s8_t ah = *(const s8_t*)(KH + qrow * KSTRB + aoff);
        s8_t al = *(const s8_t*)(KL + qrow * KSTRB + aoff);
        #pragma unroll
        for (int t = 0; t < 8; ++t) {
            int key = t * 16 + cc;
            s8_t bh = *(const s8_t*)(KH + key * KSTRB + aoff);
            s8_t bl = *(const s8_t*)(KL + key * KSTRB + aoff);
            acc[t] = __builtin_amdgcn_mfma_f32_16x16x32_bf16(ah, bh, acc[t], 0, 0, 0);
            acc[t] = __builtin_amdgcn_mfma_f32_16x16x32_bf16(ah, bl, acc[t], 0, 0, 0);
            acc[t] = __builtin_amdgcn_mfma_f32_16x16x32_bf16(al, bh, acc[t], 0, 0, 0);
        }
    }

    // ---- scale + self-mask + softmax
    int tqi[4];
    float sc[4];
    #pragma unroll
    for (int g = 0; g < 4; ++g) {
        int q = wv * 16 + quad * 4 + g;
        tqi[g] = tkx[q];
        sc[g] = nrm_s[q] * 0.125f;
    }
    int tki[8];
    #pragma unroll
    for (int t = 0; t < 8; ++t) tki[t] = tkx[t * 16 + cc];

    #pragma unroll
    for (int t = 0; t < 8; ++t)
        #pragma unroll
        for (int g = 0; g < 4; ++g) {
            float d = acc[t][g] * sc[g];
            if (tqi[g] == tki[t]) d = -1e5f;
            acc[t][g] = d;
        }

    float mx[4];
    #pragma unroll
    for (int g = 0; g < 4; ++g) {
        float m = acc[0][g];
        #pragma unroll
        for (int t = 1; t < 8; ++t) m = fmaxf(m, acc[t][g]);
        mx[g] = m;
    }
    #pragma unroll
    for (int msk = 1; msk <= 8; msk <<= 1)
        #pragma unroll
        for (int g = 0; g < 4; ++g) mx[g] = fmaxf(mx[g], __shfl_xor(mx[g], msk, 64));

    float sm[4] = {0.f, 0.f, 0.f, 0.f};
    #pragma unroll
    for (int t = 0; t < 8; ++t)
        #pragma unroll
        for (int g = 0; g < 4; ++g) {
            float p = expf(acc[t][g] - mx[g]);
            acc[t][g] = p;
            sm[g] += p;
        }
    #pragma unroll
    for (int msk = 1; msk <= 8; msk <<= 1)
        #pragma unroll
        for (int g = 0; g < 4; ++g) sm[g] += __shfl_xor(sm[g], msk, 64);

    float pinv[4];
    #pragma unroll
    for (int g = 0; g < 4; ++g) pinv[g] = 1.0f / sm[g];

    if (cc == 0) {
        #pragma unroll
        for (int g = 0; g < 4; ++g)
            logits_ws[sbase + h * S + tqi[g]] = mx[g] + logf(sm[g]);
    }

    // ---- P -> packed split-bf16 dwords into LDS (overlaying KH/KL)
    __syncthreads();
    #pragma unroll
    for (int t = 0; t < 8; ++t) {
        int key = t * 16 + cc;
        #pragma unroll
        for (int g = 0; g < 4; ++g) {
            int q = wv * 16 + quad * 4 + g;
            float p = acc[t][g] * pinv[g];
            unsigned short hh, ll;
            split_bf16(p, hh, ll);
            PHLd[q * PVSTRD + key] = (unsigned int)hh | ((unsigned int)ll << 16);
        }
    }
    __syncthreads();

    // ---- PV via split-bf16 MFMA (A = P rows, B = Vt rows), perm-unpacked
    f4_t oacc[4];
    #pragma unroll
    for (int n = 0; n < 4; ++n) oacc[n] = (f4_t){0.f,0.f,0.f,0.f};

    #pragma unroll
    for (int kc = 0; kc < 4; ++kc) {
        int k0 = kc * 32 + quad * 8;
        const unsigned int* prow = PHLd + (wv * 16 + cc) * PVSTRD + k0;
        uint4 ra = *(const uint4*)prow;
        uint4 rb = *(const uint4*)(prow + 4);
        s8_t pah = mk_frag(ra, rb, SEL_HI);
        s8_t pal = mk_frag(ra, rb, SEL_LO);
        #pragma unroll
        for (int n = 0; n < 4; ++n) {
            const unsigned int* vrow = VHLd + (n * 16 + cc) * PVSTRD + k0;
            uint4 va = *(const uint4*)vrow;
            uint4 vb = *(const uint4*)(vrow + 4);
            s8_t vh = mk_frag(va, vb, SEL_HI);
            s8_t vl = mk_frag(va, vb, SEL_LO);
            oacc[n] = __builtin_amdgcn_mfma_f32_16x16x32_bf16(pah, vh, oacc[n], 0, 0, 0);
            oacc[n] = __builtin_amdgcn_mfma_f32_16x16x32_bf16(pal, vh, oacc[n], 0, 0, 0);
            oacc[n] = __builtin_amdgcn_mfma_f32_16x16x32_bf16(pah, vl, oacc[n], 0, 0, 0);
        }
    }

    // ---- write O
    #pragma unroll
    for (int g = 0; g < 4; ++g) {
        float* op = o_ws + ((size_t)(sbase + h * S + tqi[g])) * D;
        #pragma unroll
        for (int n = 0; n < 4; ++n)
            op[n * 16 + cc] = oacc[n][g];
    }
}

// ---------------------------------------------------------------------------
// Kernel 4: combine hash rounds with softmax(logits) weights.
// ---------------------------------------------------------------------------
__global__ __launch_bounds__(256) void combine_kernel(
    const float* __restrict__ o_ws, const float* __restrict__ logits_ws,
    float* __restrict__ out)
{
    int gid = blockIdx.x * 256 + threadIdx.x;
    int token = gid >> 4;          // b*S + t
    int d4 = gid & 15;
    int b = token >> 12;
    int t = token & (S - 1);
    int base = b * (NH * S) + t;

    float l[8];
    #pragma unroll
    for (int hh = 0; hh < 8; ++hh) l[hh] = logits_ws[base + hh * S];
    float m = l[0];
    #pragma unroll
    for (int hh = 1; hh < 8; ++hh) m = fmaxf(m, l[hh]);
    float w[8]; float ssum = 0.f;
    #pragma unroll
    for (int hh = 0; hh < 8; ++hh) { w[hh] = expf(l[hh] - m); ssum += w[hh]; }
    float inv = 1.0f / ssum;

    float4 acc = {0,0,0,0};
    #pragma unroll
    for (int hh = 0; hh < 8; ++hh) {
        const float4 ov = ((const float4*)o_ws)[(size_t)(base + hh * S) * 16 + d4];
        float wh = w[hh] * inv;
        acc.x += wh * ov.x; acc.y += wh * ov.y; acc.z += wh * ov.z; acc.w += wh * ov.w;
    }
    ((float4*)out)[(size_t)token * 16 + d4] = acc;
}

// ---------------------------------------------------------------------------
extern "C" void kernel_launch(void* const* d_in, const int* in_sizes, int n_in,
                              void* d_out, int out_size, void* d_ws, size_t ws_size,
                              hipStream_t stream) {
    const float* qk  = (const float*)d_in[0];
    const float* v   = (const float*)d_in[1];
    const float* rot = (const float*)d_in[2];

    float* out         = (float*)d_out;
    float* out_buckets = out + (size_t)B * S * D;

    int*   bucket_ws = (int*)d_ws;
    int*   st_ws     = bucket_ws + (size_t)B * NH * S;
    float* logits_ws = (float*)(st_ws + (size_t)B * NH * S);
    float* o_ws      = logits_ws + (size_t)B * NH * S;

    hash_kernel<<<B * NH * 4, 256, 0, stream>>>(qk, rot, out_buckets, bucket_ws);
    sort_kernel<<<B * NH, 256, 0, stream>>>(bucket_ws, st_ws);
    attn_kernel<<<B * CHUNKS, 256, 0, stream>>>(qk, v, st_ws, o_ws, logits_ws);
    combine_kernel<<<(B * S * 16) / 256, 256, 0, stream>>>(o_ws, logits_ws, out);
}

// Round 5
// 261.365 us; speedup vs baseline: 4.3923x; 1.2646x over previous
//
#include <hip/hip_runtime.h>
#include <hip/hip_bf16.h>
#include <math.h>

// Problem constants
#define B 16
#define S 4096
#define D 64
#define NH 8
#define NBUCK 64          // buckets per hash
#define CHUNKS 512        // chunks per batch (NH * NBUCK)
#define BS 64             // bucket/chunk size

typedef __attribute__((ext_vector_type(8))) short s8_t;   // 8 bf16 (4 VGPRs)
typedef __attribute__((ext_vector_type(4))) float f4_t;   // MFMA C/D

__device__ inline unsigned short bf16_rne(float x) {
    unsigned int u = __float_as_uint(x);
    u += 0x7fffu + ((u >> 16) & 1u);
    return (unsigned short)(u >> 16);
}
__device__ inline unsigned int pack_bf16_pair(float x0, float x1) {
    return (unsigned int)bf16_rne(x0) | ((unsigned int)bf16_rne(x1) << 16);
}

// ---------------------------------------------------------------------------
// Kernel 1: hashing (f64, register-blocked: 4 tokens/lane x 16 outputs x 2
// passes). FMA order per (i,f) identical to the naive version -> bit-identical
// buckets vs the R1-R4 versions.
// ---------------------------------------------------------------------------
__global__ __launch_bounds__(256) void hash_kernel(
    const float* __restrict__ qk, const float* __restrict__ rot,
    float* __restrict__ out_buckets, int* __restrict__ bucket_ws)
{
    __shared__ double R[64 * 32];   // R[f*32+i], 16 KB
    int tid = threadIdx.x;
    int bid = blockIdx.x;
    int b   = bid >> 5;
    int h   = (bid >> 2) & 7;
    int qtr = bid & 3;

    for (int e = tid; e < 2048; e += 256) {
        int f = e >> 5, i = e & 31;
        R[e] = (double)rot[f * (NH * 32) + h * 32 + i];
    }
    __syncthreads();

    const float4* rowp[4];
    #pragma unroll
    for (int j = 0; j < 4; ++j) {
        int t = qtr * 1024 + j * 256 + tid;
        rowp[j] = (const float4*)(qk + ((size_t)b * S + t) * D);
    }

    double bestv[4], worstv[4];
    int bi[4], wi[4];

    for (int p = 0; p < 2; ++p) {
        double acc[64];   // acc[i*4+j], i in 0..15 (outputs p*16+i)
        #pragma unroll
        for (int e = 0; e < 64; ++e) acc[e] = 0.0;

        for (int fc = 0; fc < 16; ++fc) {
            float xf[4][4];
            #pragma unroll
            for (int j = 0; j < 4; ++j) {
                float4 x4 = rowp[j][fc];
                xf[j][0] = x4.x; xf[j][1] = x4.y; xf[j][2] = x4.z; xf[j][3] = x4.w;
            }
            #pragma unroll
            for (int u = 0; u < 4; ++u) {
                int f = fc * 4 + u;
                const double2* Rr = (const double2*)&R[f * 32 + p * 16];
                double xd[4];
                #pragma unroll
                for (int j = 0; j < 4; ++j) xd[j] = (double)xf[j][u];
                #pragma unroll
                for (int ii = 0; ii < 8; ++ii) {
                    double2 r2 = Rr[ii];
                    #pragma unroll
                    for (int j = 0; j < 4; ++j) {
                        acc[(2*ii)*4 + j]   = __fma_rn(xd[j], r2.x, acc[(2*ii)*4 + j]);
                        acc[(2*ii+1)*4 + j] = __fma_rn(xd[j], r2.y, acc[(2*ii+1)*4 + j]);
                    }
                }
            }
        }
        #pragma unroll
        for (int i = 0; i < 16; ++i) {
            int gi = p * 16 + i;
            #pragma unroll
            for (int j = 0; j < 4; ++j) {
                double vv = acc[i*4 + j];
                if (p == 0 && i == 0) {
                    bestv[j] = vv; bi[j] = 0; worstv[j] = vv; wi[j] = 0;
                } else {
                    if (vv > bestv[j])  { bestv[j] = vv; bi[j] = gi; }
                    if (vv < worstv[j]) { worstv[j] = vv; wi[j] = gi; }
                }
            }
        }
    }

    #pragma unroll
    for (int j = 0; j < 4; ++j) {
        int t = qtr * 1024 + j * 256 + tid;
        int bucket = (-worstv[j] > bestv[j]) ? (32 + wi[j]) : bi[j];
        size_t idx = (size_t)(b * NH + h) * S + t;
        bucket_ws[idx] = bucket;
        out_buckets[idx] = (float)(bucket + h * NBUCK);
    }
}

// ---------------------------------------------------------------------------
// Kernel 2: parallel stable counting sort per (b,h). 256 threads (4 waves).
// ---------------------------------------------------------------------------
__global__ __launch_bounds__(256) void sort_kernel(
    const int* __restrict__ bucket_ws, int* __restrict__ st_ws)
{
    __shared__ int sb[S];
    __shared__ int hist[4][64];
    __shared__ int bpref[64];
    __shared__ int woff[4][64];

    int tid  = threadIdx.x;
    int wv   = tid >> 6;
    int lane = tid & 63;
    int base = blockIdx.x * S;

    hist[wv][lane] = 0;
    __syncthreads();

    int qbase = wv * 1024;
    #pragma unroll
    for (int i = 0; i < 16; ++i) {
        int t = qbase + i * 64 + lane;
        int v = bucket_ws[base + t];
        sb[t] = v;
        atomicAdd(&hist[wv][v], 1);
    }
    __syncthreads();

    if (wv == 0) {
        int total = hist[0][lane] + hist[1][lane] + hist[2][lane] + hist[3][lane];
        int x = total;
        #pragma unroll
        for (int off = 1; off < 64; off <<= 1) {
            int y = __shfl_up(x, off, 64);
            if (lane >= off) x += y;
        }
        bpref[lane] = x - total;
    }
    __syncthreads();
    {
        int o = bpref[lane];
        for (int w2 = 0; w2 < 4; ++w2) {
            if (w2 < wv) o += hist[w2][lane];
        }
        woff[wv][lane] = o;
    }
    __syncthreads();

    for (int g = 0; g < 16; ++g) {
        int t = qbase + g * 64 + lane;
        int v = sb[t];

        unsigned long long m = ~0ULL;
        #pragma unroll
        for (int bit = 0; bit < 6; ++bit) {
            unsigned long long bm = __ballot((v >> bit) & 1);
            m &= ((v >> bit) & 1) ? bm : ~bm;
        }
        unsigned long long below = (lane == 63) ? ~0ULL >> 1
                                 : ((1ULL << lane) - 1ULL);
        int rank = __popcll(m & below);
        int cnt  = __popcll(m);

        int pos = woff[wv][v] + rank;
        st_ws[base + pos] = t;

        if ((m & below) == 0ULL)
            woff[wv][v] += cnt;
        __builtin_amdgcn_s_waitcnt(0);
    }
}

// ---------------------------------------------------------------------------
// Kernel 3: per-chunk attention, plain-bf16 MFMA (error ~1e-2 << threshold).
// LDS layout (37888 B -> 4 blocks/CU):
//   K  [128 rows][144 B] @0      (18432)  normalized keys bf16
//                                 -- rows 0..63 overlaid by P[64][144B] post-dots
//   VtP[64 rows][288 B]  @18432  (18432)  V^T packed: dword = keys(2a,2a+1)
//   nrm @36864 (512), tkx @37376 (512)
// ---------------------------------------------------------------------------
#define OFF_VT 18432
#define OFF_NRM 36864
#define OFF_TKX 37376
#define LDS_TOT 37888
#define KSTRB 144     // K/P row stride bytes (72 bf16), 16B-aligned
#define VSTRD 72      // VtP row stride in dwords (288 B)

__global__ __launch_bounds__(256, 4) void attn_kernel(
    const float* __restrict__ qk, const float* __restrict__ v,
    const int* __restrict__ st_ws,
    __hip_bfloat16* __restrict__ o_ws, float* __restrict__ logits_ws)
{
    __shared__ char lds[LDS_TOT];
    float* nrm_s = (float*)(lds + OFF_NRM);
    int*   tkx   = (int*)(lds + OFF_TKX);
    unsigned int* VtP = (unsigned int*)(lds + OFF_VT);

    int tid = threadIdx.x;
    int c = blockIdx.x & (CHUNKS - 1);
    int b = blockIdx.x >> 9;
    int h = c >> 6;
    int sbase = b * (NH * S);

    if (tid < 128) {
        int cc2 = (tid < 64) ? c : ((c + CHUNKS - 1) & (CHUNKS - 1));
        tkx[tid] = st_ws[sbase + cc2 * BS + (tid & 63)];
    }
    __syncthreads();

    // ---- stage K (normalized bf16, row-major) ----
    {
        int r = tid >> 1, half = tid & 1;
        int tok = tkx[r];
        const float4* qs = (const float4*)(qk + ((size_t)b * S + tok) * D) + half * 8;
        float xq[32];
        #pragma unroll
        for (int e4 = 0; e4 < 8; ++e4) {
            float4 a = qs[e4];
            xq[e4*4+0]=a.x; xq[e4*4+1]=a.y; xq[e4*4+2]=a.z; xq[e4*4+3]=a.w;
        }
        float ss = 0.f;
        #pragma unroll
        for (int e = 0; e < 32; ++e) ss += xq[e]*xq[e];
        ss += __shfl_xor(ss, 1);
        float nr = sqrtf(ss);
        float inv = 1.0f / fmaxf(nr, 1e-12f);
        if (!half) nrm_s[r] = nr;

        unsigned int pk[16];
        #pragma unroll
        for (int e = 0; e < 16; ++e)
            pk[e] = pack_bf16_pair(xq[2*e] * inv, xq[2*e+1] * inv);
        char* kb = lds + r * KSTRB + half * 64;
        #pragma unroll
        for (int e4 = 0; e4 < 4; ++e4)
            *(uint4*)(kb + e4*16) = make_uint4(pk[e4*4], pk[e4*4+1], pk[e4*4+2], pk[e4*4+3]);
    }
    // ---- stage V^T packed (dword = 2 consecutive keys) ----
    {
        int a = tid & 63, sub = tid >> 6;     // a = key pair, sub = dim quarter
        int tok0 = tkx[2*a], tok1 = tkx[2*a+1];
        const float4* v0 = (const float4*)(v + ((size_t)b * S + tok0) * D + sub * 16);
        const float4* v1 = (const float4*)(v + ((size_t)b * S + tok1) * D + sub * 16);
        float x0[16], x1[16];
        #pragma unroll
        for (int e4 = 0; e4 < 4; ++e4) {
            float4 p0 = v0[e4], p1 = v1[e4];
            x0[e4*4+0]=p0.x; x0[e4*4+1]=p0.y; x0[e4*4+2]=p0.z; x0[e4*4+3]=p0.w;
            x1[e4*4+0]=p1.x; x1[e4*4+1]=p1.y; x1[e4*4+2]=p1.z; x1[e4*4+3]=p1.w;
        }
        #pragma unroll
        for (int e = 0; e < 16; ++e) {
            int dd = sub * 16 + e;
            VtP[dd * VSTRD + a] = pack_bf16_pair(x0[e], x1[e]);
        }
    }
    __syncthreads();

    int wv   = tid >> 6;
    int lane = tid & 63;
    int quad = lane >> 4;
    int cc   = lane & 15;

    // ---- dots: QK^T via bf16 MFMA ----
    int qrow = wv * 16 + cc;
    f4_t acc[8];
    #pragma unroll
    for (int t = 0; t < 8; ++t) acc[t] = (f4_t){0.f,0.f,0.f,0.f};

    #pragma unroll
    for (int kc = 0; kc < 2; ++kc) {
        int aoff = kc * 64 + quad * 16;
        s8_t av = *(const s8_t*)(lds + qrow * KSTRB + aoff);
        #pragma unroll
        for (int t = 0; t < 8; ++t) {
            s8_t bv = *(const s8_t*)(lds + (t * 16 + cc) * KSTRB + aoff);
            acc[t] = __builtin_amdgcn_mfma_f32_16x16x32_bf16(av, bv, acc[t], 0, 0, 0);
        }
    }

    // ---- scale + self-mask + softmax ----
    int tqi[4];
    float sc[4];
    #pragma unroll
    for (int g = 0; g < 4; ++g) {
        int q = wv * 16 + quad * 4 + g;
        tqi[g] = tkx[q];
        sc[g] = nrm_s[q] * 0.125f;
    }
    int tki[8];
    #pragma unroll
    for (int t = 0; t < 8; ++t) tki[t] = tkx[t * 16 + cc];

    #pragma unroll
    for (int t = 0; t < 8; ++t)
        #pragma unroll
        for (int g = 0; g < 4; ++g) {
            float d = acc[t][g] * sc[g];
            if (tqi[g] == tki[t]) d = -1e5f;
            acc[t][g] = d;
        }

    float mx[4];
    #pragma unroll
    for (int g = 0; g < 4; ++g) {
        float m = acc[0][g];
        #pragma unroll
        for (int t = 1; t < 8; ++t) m = fmaxf(m, acc[t][g]);
        mx[g] = m;
    }
    #pragma unroll
    for (int msk = 1; msk <= 8; msk <<= 1)
        #pragma unroll
        for (int g = 0; g < 4; ++g) mx[g] = fmaxf(mx[g], __shfl_xor(mx[g], msk, 64));

    float sm[4] = {0.f, 0.f, 0.f, 0.f};
    #pragma unroll
    for (int t = 0; t < 8; ++t)
        #pragma unroll
        for (int g = 0; g < 4; ++g) {
            float p = __expf(acc[t][g] - mx[g]);
            acc[t][g] = p;
            sm[g] += p;
        }
    #pragma unroll
    for (int msk = 1; msk <= 8; msk <<= 1)
        #pragma unroll
        for (int g = 0; g < 4; ++g) sm[g] += __shfl_xor(sm[g], msk, 64);

    float pinv[4];
    #pragma unroll
    for (int g = 0; g < 4; ++g) pinv[g] = 1.0f / sm[g];

    if (cc == 0) {
        #pragma unroll
        for (int g = 0; g < 4; ++g)
            logits_ws[sbase + h * S + tqi[g]] = mx[g] + __logf(sm[g]);
    }

    // ---- P -> bf16 into LDS, overlaying K rows 0..63.
    // Barrier: all waves must finish reading K (dots) before overlay.
    // After the write, each wave reads only its own 16 P rows -> no 2nd barrier.
    __syncthreads();
    #pragma unroll
    for (int t = 0; t < 8; ++t) {
        int key = t * 16 + cc;
        #pragma unroll
        for (int g = 0; g < 4; ++g) {
            int q = wv * 16 + quad * 4 + g;
            *(unsigned short*)(lds + q * KSTRB + key * 2) =
                bf16_rne(acc[t][g] * pinv[g]);
        }
    }

    // ---- PV via bf16 MFMA (A = P rows [own wave's], B = VtP rows) ----
    f4_t oacc[4];
    #pragma unroll
    for (int n = 0; n < 4; ++n) oacc[n] = (f4_t){0.f,0.f,0.f,0.f};

    #pragma unroll
    for (int kc = 0; kc < 4; ++kc) {
        int koff = kc * 64 + quad * 16;   // byte offset: key k at byte 2k
        s8_t pa = *(const s8_t*)(lds + (wv * 16 + cc) * KSTRB + koff);
        #pragma unroll
        for (int n = 0; n < 4; ++n) {
            s8_t bv = *(const s8_t*)((const char*)(VtP + (n * 16 + cc) * VSTRD) + koff);
            oacc[n] = __builtin_amdgcn_mfma_f32_16x16x32_bf16(pa, bv, oacc[n], 0, 0, 0);
        }
    }

    // ---- write O (bf16) ----
    #pragma unroll
    for (int g = 0; g < 4; ++g) {
        __hip_bfloat16* op = o_ws + ((size_t)(sbase + h * S + tqi[g])) * D;
        #pragma unroll
        for (int n = 0; n < 4; ++n) {
            unsigned short bits = bf16_rne(oacc[n][g]);
            *(unsigned short*)(op + n * 16 + cc) = bits;
        }
    }
}

// ---------------------------------------------------------------------------
// Kernel 4: combine hash rounds with softmax(logits) weights. o_ws is bf16.
// thread = (token, d8): 8 dims per thread.
// ---------------------------------------------------------------------------
__global__ __launch_bounds__(256) void combine_kernel(
    const __hip_bfloat16* __restrict__ o_ws, const float* __restrict__ logits_ws,
    float* __restrict__ out)
{
    int gid = blockIdx.x * 256 + threadIdx.x;
    int token = gid >> 3;          // b*S + t
    int d8 = gid & 7;
    int b = token >> 12;
    int t = token & (S - 1);
    int base = b * (NH * S) + t;

    float l[8];
    #pragma unroll
    for (int hh = 0; hh < 8; ++hh) l[hh] = logits_ws[base + hh * S];
    float m = l[0];
    #pragma unroll
    for (int hh = 1; hh < 8; ++hh) m = fmaxf(m, l[hh]);
    float w[8]; float ssum = 0.f;
    #pragma unroll
    for (int hh = 0; hh < 8; ++hh) { w[hh] = __expf(l[hh] - m); ssum += w[hh]; }
    float inv = 1.0f / ssum;

    float accv[8] = {0,0,0,0,0,0,0,0};
    #pragma unroll
    for (int hh = 0; hh < 8; ++hh) {
        uint4 pk = *(const uint4*)(o_ws + (size_t)(base + hh * S) * D + d8 * 8);
        float wh = w[hh] * inv;
        unsigned int ws_[4] = {pk.x, pk.y, pk.z, pk.w};
        #pragma unroll
        for (int e = 0; e < 4; ++e) {
            float lo = __uint_as_float(ws_[e] << 16);
            float hi = __uint_as_float(ws_[e] & 0xffff0000u);
            accv[2*e]   += wh * lo;
            accv[2*e+1] += wh * hi;
        }
    }
    float4* op = (float4*)(out + (size_t)token * D + d8 * 8);
    op[0] = make_float4(accv[0], accv[1], accv[2], accv[3]);
    op[1] = make_float4(accv[4], accv[5], accv[6], accv[7]);
}

// ---------------------------------------------------------------------------
extern "C" void kernel_launch(void* const* d_in, const int* in_sizes, int n_in,
                              void* d_out, int out_size, void* d_ws, size_t ws_size,
                              hipStream_t stream) {
    const float* qk  = (const float*)d_in[0];
    const float* v   = (const float*)d_in[1];
    const float* rot = (const float*)d_in[2];

    float* out         = (float*)d_out;
    float* out_buckets = out + (size_t)B * S * D;

    int*   bucket_ws = (int*)d_ws;
    int*   st_ws     = bucket_ws + (size_t)B * NH * S;
    float* logits_ws = (float*)(st_ws + (size_t)B * NH * S);
    __hip_bfloat16* o_ws = (__hip_bfloat16*)(logits_ws + (size_t)B * NH * S);

    hash_kernel<<<B * NH * 4, 256, 0, stream>>>(qk, rot, out_buckets, bucket_ws);
    sort_kernel<<<B * NH, 256, 0, stream>>>(bucket_ws, st_ws);
    attn_kernel<<<B * CHUNKS, 256, 0, stream>>>(qk, v, st_ws, o_ws, logits_ws);
    combine_kernel<<<(B * S * 8) / 256, 256, 0, stream>>>(o_ws, logits_ws, out);
}